// Round 13
// baseline (177.519 us; speedup 1.0000x reference)
//
#include <hip/hip_runtime.h>
#include <hip/hip_bf16.h>

#define NN 8192
#define DIM 128
#define KS 8            // split-K factor for PV
#define KSL (NN / KS)   // 1024 k per slice
#define RPB 64          // rows per SB block
#define KC 256          // k-chunk width in SB (wave-row contiguous writes)

typedef __attribute__((ext_vector_type(8))) short bf16x8;
typedef __attribute__((ext_vector_type(4))) float f32x4;
typedef __attribute__((ext_vector_type(4))) int i32x4;
typedef __attribute__((ext_vector_type(4))) unsigned int u32x4;
typedef __attribute__((ext_vector_type(4))) unsigned short u16x4;
typedef __attribute__((ext_vector_type(4))) short s16x4;

static __device__ inline unsigned short f2bf(float x) {
    __hip_bfloat16 b = __float2bfloat16(x);
    return *reinterpret_cast<unsigned short*>(&b);
}

struct BSplit { short hi, lo; };
static __device__ inline BSplit bsplit(float x) {
    BSplit r;
    __hip_bfloat16 h = __float2bfloat16(x);
    r.hi = *reinterpret_cast<short*>(&h);
    float rem = x - __bfloat162float(h);
    __hip_bfloat16 l = __float2bfloat16(rem);
    r.lo = *reinterpret_cast<short*>(&l);
    return r;
}

// ---------------------------------------------------------------------------
// K1M: Wh = h@W^T (split-bf16 MFMA, f32-grade), a1/a2 from the f32
// accumulators, packed tables pk[i] = {a2, bf16(E1)|bf16(E2)<<16}, and
// whbT (bf16, tiled [k>>3][dim][k&7]). grid 128 x 64 rows, 4 waves.
// ---------------------------------------------------------------------------
__global__ __launch_bounds__(256) void k1m(const float* __restrict__ h,
                                           const float* __restrict__ W,
                                           const float* __restrict__ a,
                                           __hip_bfloat16* __restrict__ whbT,
                                           float* __restrict__ a1g,
                                           float2* __restrict__ pk) {
    __shared__ short whi[128 * 132];         // W hi, row stride 132 (264B)
    __shared__ short wlo[128 * 132];         // W lo
    __shared__ short wt[8 * 128 * 8];        // whbT retile staging (16 KB)
    __shared__ float a_sh[256];

    const int tid = threadIdx.x;
    const int wv = tid >> 6, lane = tid & 63;
    const int r0 = blockIdx.x * 64;

    for (int idx = tid; idx < 128 * 128; idx += 256) {
        const int d = idx >> 7, k = idx & 127;
        BSplit s = bsplit(W[idx]);
        whi[d * 132 + k] = s.hi;
        wlo[d * 132 + k] = s.lo;
    }
    a_sh[tid] = a[tid];
    __syncthreads();

    f32x4 acc[8];
    #pragma unroll
    for (int n = 0; n < 8; ++n) acc[n] = (f32x4){0.f, 0.f, 0.f, 0.f};

    const int arow = r0 + wv * 16 + (lane & 15);
    const int ksub = (lane >> 4) * 8;
    const float* hp = h + (size_t)arow * DIM + ksub;

    #pragma unroll
    for (int kk = 0; kk < 128; kk += 32) {
        f32x4 x0 = *(const f32x4*)(hp + kk);
        f32x4 x1 = *(const f32x4*)(hp + kk + 4);
        bf16x8 ah, al;
        {
            BSplit s0 = bsplit(x0.x), s1 = bsplit(x0.y), s2 = bsplit(x0.z), s3 = bsplit(x0.w);
            BSplit s4 = bsplit(x1.x), s5 = bsplit(x1.y), s6 = bsplit(x1.z), s7 = bsplit(x1.w);
            ah[0] = s0.hi; al[0] = s0.lo; ah[1] = s1.hi; al[1] = s1.lo;
            ah[2] = s2.hi; al[2] = s2.lo; ah[3] = s3.hi; al[3] = s3.lo;
            ah[4] = s4.hi; al[4] = s4.lo; ah[5] = s5.hi; al[5] = s5.lo;
            ah[6] = s6.hi; al[6] = s6.lo; ah[7] = s7.hi; al[7] = s7.lo;
        }
        #pragma unroll
        for (int n = 0; n < 8; ++n) {
            const int boff = (n * 16 + (lane & 15)) * 132 + kk + ksub;
            bf16x8 bh = *(const bf16x8*)(whi + boff);
            bf16x8 bl = *(const bf16x8*)(wlo + boff);
            acc[n] = __builtin_amdgcn_mfma_f32_16x16x32_bf16(ah, bh, acc[n], 0, 0, 0);
            acc[n] = __builtin_amdgcn_mfma_f32_16x16x32_bf16(ah, bl, acc[n], 0, 0, 0);
            acc[n] = __builtin_amdgcn_mfma_f32_16x16x32_bf16(al, bh, acc[n], 0, 0, 0);
        }
    }

    float p1[4] = {0.f, 0.f, 0.f, 0.f}, p2[4] = {0.f, 0.f, 0.f, 0.f};
    #pragma unroll
    for (int n = 0; n < 8; ++n) {
        const float av1 = a_sh[n * 16 + (lane & 15)];
        const float av2 = a_sh[128 + n * 16 + (lane & 15)];
        #pragma unroll
        for (int q = 0; q < 4; ++q) {
            p1[q] += acc[n][q] * av1;
            p2[q] += acc[n][q] * av2;
        }
    }
    #pragma unroll
    for (int o = 8; o >= 1; o >>= 1) {
        #pragma unroll
        for (int q = 0; q < 4; ++q) {
            p1[q] += __shfl_xor(p1[q], o, 64);
            p2[q] += __shfl_xor(p2[q], o, 64);
        }
    }
    if ((lane & 15) == 0) {
        #pragma unroll
        for (int q = 0; q < 4; ++q) {
            const int row = r0 + wv * 16 + (lane >> 4) * 4 + q;
            a1g[row] = p1[q];
            const float E1v = expf(p2[q]);
            const float E2v = expf(0.2f * p2[q]);
            unsigned ub = (unsigned)f2bf(E1v) | ((unsigned)f2bf(E2v) << 16);
            float2 pv;
            pv.x = p2[q];
            pv.y = __uint_as_float(ub);
            pk[row] = pv;
        }
    }

    #pragma unroll
    for (int n = 0; n < 8; ++n) {
        #pragma unroll
        for (int q = 0; q < 4; ++q) {
            const int kloc = wv * 16 + (lane >> 4) * 4 + q;   // block-local k
            const int d = n * 16 + (lane & 15);
            wt[(kloc >> 3) * 1024 + d * 8 + (kloc & 7)] = (short)f2bf(acc[n][q]);
        }
    }
    __syncthreads();
    short* dst = reinterpret_cast<short*>(whbT) + ((size_t)r0 << 7);
    for (int idx = tid * 4; idx < 8192; idx += 1024)
        *(s16x4*)(dst + idx) = *(const s16x4*)(wt + idx);
}

// ---------------------------------------------------------------------------
// SA: stream adj, 4x batched issue per 1024-col super-iteration. Bit layout:
// col j -> word (j>>8)*8 + ((j>>7)&1)*4 + (j&3), bit (j>>2)&31.
// ---------------------------------------------------------------------------
static __device__ inline void sa_group(const i32x4 v, const f32x4 pa, const f32x4 pb,
                                       const float a1i, const int lane,
                                       float& s1, float& s2,
                                       unsigned* __restrict__ bgrp) {
    unsigned long long m0 = __ballot(v.x != 0);
    unsigned long long m1 = __ballot(v.y != 0);
    unsigned long long m2 = __ballot(v.z != 0);
    unsigned long long m3 = __ballot(v.w != 0);
    if (lane == 0) {
        u32x4 w;
        w.x = (unsigned)m0; w.y = (unsigned)m1;
        w.z = (unsigned)m2; w.w = (unsigned)m3;
        *(u32x4*)(bgrp) = w;
    } else if (lane == 32) {
        u32x4 w;
        w.x = (unsigned)(m0 >> 32); w.y = (unsigned)(m1 >> 32);
        w.z = (unsigned)(m2 >> 32); w.w = (unsigned)(m3 >> 32);
        *(u32x4*)(bgrp + 4) = w;
    }
    float x2, e1, e2; unsigned ub; bool px;
    x2 = pa.x; ub = __float_as_uint(pa.y);
    e1 = __uint_as_float(ub << 16); e2 = __uint_as_float(ub & 0xffff0000u);
    px = (a1i + x2 >= 0.f);
    s1 += (v.x && px) ? e1 : 0.f;  s2 += (v.x && !px) ? e2 : 0.f;
    x2 = pa.z; ub = __float_as_uint(pa.w);
    e1 = __uint_as_float(ub << 16); e2 = __uint_as_float(ub & 0xffff0000u);
    px = (a1i + x2 >= 0.f);
    s1 += (v.y && px) ? e1 : 0.f;  s2 += (v.y && !px) ? e2 : 0.f;
    x2 = pb.x; ub = __float_as_uint(pb.y);
    e1 = __uint_as_float(ub << 16); e2 = __uint_as_float(ub & 0xffff0000u);
    px = (a1i + x2 >= 0.f);
    s1 += (v.z && px) ? e1 : 0.f;  s2 += (v.z && !px) ? e2 : 0.f;
    x2 = pb.z; ub = __float_as_uint(pb.w);
    e1 = __uint_as_float(ub << 16); e2 = __uint_as_float(ub & 0xffff0000u);
    px = (a1i + x2 >= 0.f);
    s1 += (v.w && px) ? e1 : 0.f;  s2 += (v.w && !px) ? e2 : 0.f;
}

__global__ __launch_bounds__(256) void sa_scan(const int* __restrict__ adj,
                                               const float* __restrict__ a1g,
                                               const float2* __restrict__ pk,
                                               unsigned* __restrict__ bm,
                                               float* __restrict__ crow) {
    const int wid = threadIdx.x >> 6, lane = threadIdx.x & 63;
    const int i = blockIdx.x * 4 + wid;
    const float a1i = a1g[i];
    const int* arow = adj + (size_t)i * NN;
    unsigned* brow = bm + (size_t)i * (NN / 32);
    const float* pkf = reinterpret_cast<const float*>(pk);

    float s1 = 0.f, s2 = 0.f;
    for (int it = 0; it < NN / 1024; ++it) {
        const int j0 = it * 1024 + lane * 4;
        i32x4 v0 = __builtin_nontemporal_load((const i32x4*)(arow + j0));
        i32x4 v1 = __builtin_nontemporal_load((const i32x4*)(arow + j0 + 256));
        i32x4 v2 = __builtin_nontemporal_load((const i32x4*)(arow + j0 + 512));
        i32x4 v3 = __builtin_nontemporal_load((const i32x4*)(arow + j0 + 768));
        f32x4 pa0 = *(const f32x4*)(pkf + 2 * j0);
        f32x4 pb0 = *(const f32x4*)(pkf + 2 * j0 + 4);
        f32x4 pa1 = *(const f32x4*)(pkf + 2 * (j0 + 256));
        f32x4 pb1 = *(const f32x4*)(pkf + 2 * (j0 + 256) + 4);
        f32x4 pa2 = *(const f32x4*)(pkf + 2 * (j0 + 512));
        f32x4 pb2 = *(const f32x4*)(pkf + 2 * (j0 + 512) + 4);
        f32x4 pa3 = *(const f32x4*)(pkf + 2 * (j0 + 768));
        f32x4 pb3 = *(const f32x4*)(pkf + 2 * (j0 + 768) + 4);
        unsigned* bsup = brow + it * 32;
        sa_group(v0, pa0, pb0, a1i, lane, s1, s2, bsup);
        sa_group(v1, pa1, pb1, a1i, lane, s1, s2, bsup + 8);
        sa_group(v2, pa2, pb2, a1i, lane, s1, s2, bsup + 16);
        sa_group(v3, pa3, pb3, a1i, lane, s1, s2, bsup + 24);
    }
    #pragma unroll
    for (int o = 32; o >= 1; o >>= 1) {
        s1 += __shfl_xor(s1, o, 64);
        s2 += __shfl_xor(s2, o, 64);
    }
    if (lane == 0) {
        float c1 = 0.f, c2 = 0.f;
        if (s1 + s2 > 0.f) {
            float e1v = expf(a1i);
            float e2v = expf(0.2f * a1i);
            float S = e1v * s1 + e2v * s2;
            c1 = e1v / S;
            c2 = e2v / S;
        }
        crow[i * 4 + 0] = c1;
        crow[i * 4 + 1] = c2;
        crow[i * 4 + 2] = a1i;
        crow[i * 4 + 3] = 0.f;
    }
}

// ---------------------------------------------------------------------------
// SB v3: fused alpha-write + PV MFMA, split-K. grid (NN/64, KS=8), 512 thr.
// WRITE PHASE IS WAVE-ROW CONTIGUOUS: per v-iter each wave owns ONE row and
// its 64 lanes x 16B cover 256 contiguous cols -> one 1-KB NT store per
// wave-inst (the fill-kernel pattern), instead of 2x512B segments 32KB apart.
// KC=256, single abuf (33.8 KB -> still 4 blocks/CU), write-bar-MFMA-bar.
// Bit extraction: p = lane&31 (valid since kc % 128 == 0).
// ---------------------------------------------------------------------------
__global__ __launch_bounds__(512, 8) void sb_pv(const unsigned* __restrict__ bm,
                                                const float* __restrict__ crowG,
                                                const float2* __restrict__ pk,
                                                const __hip_bfloat16* __restrict__ whbT,
                                                float* __restrict__ alpha,
                                                float* __restrict__ part) {
    __shared__ __hip_bfloat16 abuf[RPB][KC + 8];         // 33.8 KB
    __shared__ float crowL[RPB][4];                      // 1 KB

    const int tid = threadIdx.x;
    const int wv = tid >> 6, lane = tid & 63;
    const int r0 = blockIdx.x * RPB;
    const int ks = blockIdx.y;
    const int k0 = ks * KSL;
    const float* pkf = reinterpret_cast<const float*>(pk);

    if (tid < RPB * 4)
        crowL[tid >> 2][tid & 3] = crowG[(r0 + (tid >> 2)) * 4 + (tid & 3)];
    __syncthreads();

    f32x4 acc[4];
    #pragma unroll
    for (int rt = 0; rt < 4; ++rt) acc[rt] = (f32x4){0.f, 0.f, 0.f, 0.f};
    const int n0 = wv * 16;
    const short* wb = reinterpret_cast<const short*>(whbT);
    const short* bbase = wb + (size_t)(n0 + (lane & 15)) * 8 + (size_t)(lane >> 4) * 1024;

    const unsigned pbit = lane & 31;

    for (int kc = 0; kc < KSL; kc += KC) {
        // ---- write phase: 8 v-iters, wave wv owns row v*8+wv, 256 cols ----
        const int j = k0 + kc + lane * 4;                // per-lane col
        f32x4 pa = *(const f32x4*)(pkf + 2 * j);
        f32x4 pb = *(const f32x4*)(pkf + 2 * j + 4);
        const int wbase = (kc >> 5) + (lane >> 5) * 4;   // word off in row slice
        #pragma unroll
        for (int v = 0; v < 8; ++v) {
            const int r = v * 8 + wv;
            const int gr = r0 + r;
            u32x4 w4 = *(const u32x4*)(bm + (size_t)gr * (NN / 32) + ks * (KSL / 32) + wbase);
            f32x4 cw = *(const f32x4*)(&crowL[r][0]);    // wave-uniform broadcast
            const float c1 = cw.x, c2 = cw.y, a1i = cw.z;
            f32x4 al;
            {
                unsigned ub = __float_as_uint(pa.y);
                float e1 = __uint_as_float(ub << 16), e2 = __uint_as_float(ub & 0xffff0000u);
                al.x = ((w4.x >> pbit) & 1) ? ((a1i + pa.x >= 0.f) ? c1 * e1 : c2 * e2) : 0.f;
            }
            {
                unsigned ub = __float_as_uint(pa.w);
                float e1 = __uint_as_float(ub << 16), e2 = __uint_as_float(ub & 0xffff0000u);
                al.y = ((w4.y >> pbit) & 1) ? ((a1i + pa.z >= 0.f) ? c1 * e1 : c2 * e2) : 0.f;
            }
            {
                unsigned ub = __float_as_uint(pb.y);
                float e1 = __uint_as_float(ub << 16), e2 = __uint_as_float(ub & 0xffff0000u);
                al.z = ((w4.z >> pbit) & 1) ? ((a1i + pb.x >= 0.f) ? c1 * e1 : c2 * e2) : 0.f;
            }
            {
                unsigned ub = __float_as_uint(pb.w);
                float e1 = __uint_as_float(ub << 16), e2 = __uint_as_float(ub & 0xffff0000u);
                al.w = ((w4.w >> pbit) & 1) ? ((a1i + pb.z >= 0.f) ? c1 * e1 : c2 * e2) : 0.f;
            }
            __builtin_nontemporal_store(al, (f32x4*)(alpha + (size_t)gr * NN + j));
            u16x4 ub4;
            ub4.x = f2bf(al.x); ub4.y = f2bf(al.y); ub4.z = f2bf(al.z); ub4.w = f2bf(al.w);
            *(u16x4*)(&abuf[r][lane * 4]) = ub4;
        }
        __syncthreads();
        // ---- MFMA phase ----
        #pragma unroll
        for (int kk = 0; kk < KC; kk += 32) {
            bf16x8 bf = *(const bf16x8*)(bbase + (size_t)((k0 + kc + kk) >> 3) * 1024);
            #pragma unroll
            for (int rt = 0; rt < 4; ++rt) {
                bf16x8 af = *(const bf16x8*)(&abuf[rt * 16 + (lane & 15)][kk + 8 * (lane >> 4)]);
                acc[rt] = __builtin_amdgcn_mfma_f32_16x16x32_bf16(af, bf, acc[rt], 0, 0, 0);
            }
        }
        __syncthreads();                                 // WAR before next write
    }

    float* pb2 = part + (size_t)ks * NN * DIM;
    const int rb = (lane >> 4) * 4;
    #pragma unroll
    for (int rt = 0; rt < 4; ++rt) {
        #pragma unroll
        for (int q = 0; q < 4; ++q)
            pb2[(size_t)(r0 + rt * 16 + rb + q) * DIM + n0 + (lane & 15)] = acc[rt][q];
    }
}

// ---------------------------------------------------------------------------
// K5: reduce split-K partials -> out (vectorized; part is L2-warm)
// ---------------------------------------------------------------------------
__global__ __launch_bounds__(256) void k5_reduce(const float* __restrict__ part,
                                                 float* __restrict__ out) {
    const size_t idx = ((size_t)blockIdx.x * 256 + threadIdx.x) * 4;
    f32x4 s = (f32x4){0.f, 0.f, 0.f, 0.f};
    #pragma unroll
    for (int ks = 0; ks < KS; ++ks)
        s += *(const f32x4*)(part + (size_t)ks * NN * DIM + idx);
    *(f32x4*)(out + idx) = s;
}

// ---------------------------------------------------------------------------
extern "C" void kernel_launch(void* const* d_in, const int* in_sizes, int n_in,
                              void* d_out, int out_size, void* d_ws, size_t ws_size,
                              hipStream_t stream) {
    const float* h   = (const float*)d_in[0];
    const int*   adj = (const int*)d_in[1];
    const float* W   = (const float*)d_in[2];
    const float* a   = (const float*)d_in[3];

    float* out   = (float*)d_out;
    float* alpha = out + (size_t)NN * DIM;

    char* ws = (char*)d_ws;
    __hip_bfloat16* whbT = (__hip_bfloat16*)(ws);          // 2 MB
    float* a1g   = (float*)(ws + 0x200000);                // 32 KB
    float2* pk   = (float2*)(ws + 0x208000);               // 64 KB
    float* crow  = (float*)(ws + 0x218000);                // 128 KB
    unsigned* bm = (unsigned*)(ws + 0x240000);             // 8 MB
    float* part  = (float*)(ws + 0xA40000);                // KS*4 MB = 32 MB

    k1m<<<NN / 64, 256, 0, stream>>>(h, W, a, whbT, a1g, pk);
    sa_scan<<<NN / 4, 256, 0, stream>>>(adj, a1g, pk, bm, crow);
    sb_pv<<<dim3(NN / RPB, KS), 512, 0, stream>>>(bm, crow, pk, whbT, alpha, part);
    k5_reduce<<<NN * DIM / 1024, 256, 0, stream>>>(part, out);
}

// Round 14
// 161.508 us; speedup vs baseline: 1.0991x; 1.0991x over previous
//
#include <hip/hip_runtime.h>
#include <hip/hip_bf16.h>

#define NN 8192
#define DIM 128
#define KS 8            // split-K factor for PV
#define KSL (NN / KS)   // 1024 k per slice
#define RPB 64          // rows per SB block
#define KC 128          // k-chunk width in SB

typedef __attribute__((ext_vector_type(8))) short bf16x8;
typedef __attribute__((ext_vector_type(4))) float f32x4;
typedef __attribute__((ext_vector_type(4))) int i32x4;
typedef __attribute__((ext_vector_type(4))) unsigned int u32x4;
typedef __attribute__((ext_vector_type(4))) unsigned short u16x4;
typedef __attribute__((ext_vector_type(4))) short s16x4;

static __device__ inline unsigned short f2bf(float x) {
    __hip_bfloat16 b = __float2bfloat16(x);
    return *reinterpret_cast<unsigned short*>(&b);
}

struct BSplit { short hi, lo; };
static __device__ inline BSplit bsplit(float x) {
    BSplit r;
    __hip_bfloat16 h = __float2bfloat16(x);
    r.hi = *reinterpret_cast<short*>(&h);
    float rem = x - __bfloat162float(h);
    __hip_bfloat16 l = __float2bfloat16(rem);
    r.lo = *reinterpret_cast<short*>(&l);
    return r;
}

// ---------------------------------------------------------------------------
// K1M: Wh = h@W^T (split-bf16 MFMA, f32-grade), a1 (f32), packed table
// pku[j] = bf16(E1)|bf16(E2)<<16 (4 B/col — a2 eliminated: the leaky branch
// test a1+a2>=0 is equivalent to E1 >= exp(-a1), E1=exp(a2) monotone), and
// whbT (bf16, tiled [k>>3][dim][k&7]). grid 128 x 64 rows, 4 waves.
// ---------------------------------------------------------------------------
__global__ __launch_bounds__(256) void k1m(const float* __restrict__ h,
                                           const float* __restrict__ W,
                                           const float* __restrict__ a,
                                           __hip_bfloat16* __restrict__ whbT,
                                           float* __restrict__ a1g,
                                           unsigned* __restrict__ pku) {
    __shared__ short whi[128 * 132];         // W hi, row stride 132 (264B)
    __shared__ short wlo[128 * 132];         // W lo
    __shared__ short wt[8 * 128 * 8];        // whbT retile staging (16 KB)
    __shared__ float a_sh[256];

    const int tid = threadIdx.x;
    const int wv = tid >> 6, lane = tid & 63;
    const int r0 = blockIdx.x * 64;

    for (int idx = tid; idx < 128 * 128; idx += 256) {
        const int d = idx >> 7, k = idx & 127;
        BSplit s = bsplit(W[idx]);
        whi[d * 132 + k] = s.hi;
        wlo[d * 132 + k] = s.lo;
    }
    a_sh[tid] = a[tid];
    __syncthreads();

    f32x4 acc[8];
    #pragma unroll
    for (int n = 0; n < 8; ++n) acc[n] = (f32x4){0.f, 0.f, 0.f, 0.f};

    const int arow = r0 + wv * 16 + (lane & 15);
    const int ksub = (lane >> 4) * 8;
    const float* hp = h + (size_t)arow * DIM + ksub;

    #pragma unroll
    for (int kk = 0; kk < 128; kk += 32) {
        f32x4 x0 = *(const f32x4*)(hp + kk);
        f32x4 x1 = *(const f32x4*)(hp + kk + 4);
        bf16x8 ah, al;
        {
            BSplit s0 = bsplit(x0.x), s1 = bsplit(x0.y), s2 = bsplit(x0.z), s3 = bsplit(x0.w);
            BSplit s4 = bsplit(x1.x), s5 = bsplit(x1.y), s6 = bsplit(x1.z), s7 = bsplit(x1.w);
            ah[0] = s0.hi; al[0] = s0.lo; ah[1] = s1.hi; al[1] = s1.lo;
            ah[2] = s2.hi; al[2] = s2.lo; ah[3] = s3.hi; al[3] = s3.lo;
            ah[4] = s4.hi; al[4] = s4.lo; ah[5] = s5.hi; al[5] = s5.lo;
            ah[6] = s6.hi; al[6] = s6.lo; ah[7] = s7.hi; al[7] = s7.lo;
        }
        #pragma unroll
        for (int n = 0; n < 8; ++n) {
            const int boff = (n * 16 + (lane & 15)) * 132 + kk + ksub;
            bf16x8 bh = *(const bf16x8*)(whi + boff);
            bf16x8 bl = *(const bf16x8*)(wlo + boff);
            acc[n] = __builtin_amdgcn_mfma_f32_16x16x32_bf16(ah, bh, acc[n], 0, 0, 0);
            acc[n] = __builtin_amdgcn_mfma_f32_16x16x32_bf16(ah, bl, acc[n], 0, 0, 0);
            acc[n] = __builtin_amdgcn_mfma_f32_16x16x32_bf16(al, bh, acc[n], 0, 0, 0);
        }
    }

    float p1[4] = {0.f, 0.f, 0.f, 0.f}, p2[4] = {0.f, 0.f, 0.f, 0.f};
    #pragma unroll
    for (int n = 0; n < 8; ++n) {
        const float av1 = a_sh[n * 16 + (lane & 15)];
        const float av2 = a_sh[128 + n * 16 + (lane & 15)];
        #pragma unroll
        for (int q = 0; q < 4; ++q) {
            p1[q] += acc[n][q] * av1;
            p2[q] += acc[n][q] * av2;
        }
    }
    #pragma unroll
    for (int o = 8; o >= 1; o >>= 1) {
        #pragma unroll
        for (int q = 0; q < 4; ++q) {
            p1[q] += __shfl_xor(p1[q], o, 64);
            p2[q] += __shfl_xor(p2[q], o, 64);
        }
    }
    if ((lane & 15) == 0) {
        #pragma unroll
        for (int q = 0; q < 4; ++q) {
            const int row = r0 + wv * 16 + (lane >> 4) * 4 + q;
            a1g[row] = p1[q];
            const float E1v = expf(p2[q]);
            const float E2v = expf(0.2f * p2[q]);
            pku[row] = (unsigned)f2bf(E1v) | ((unsigned)f2bf(E2v) << 16);
        }
    }

    #pragma unroll
    for (int n = 0; n < 8; ++n) {
        #pragma unroll
        for (int q = 0; q < 4; ++q) {
            const int kloc = wv * 16 + (lane >> 4) * 4 + q;   // block-local k
            const int d = n * 16 + (lane & 15);
            wt[(kloc >> 3) * 1024 + d * 8 + (kloc & 7)] = (short)f2bf(acc[n][q]);
        }
    }
    __syncthreads();
    short* dst = reinterpret_cast<short*>(whbT) + ((size_t)r0 << 7);
    for (int idx = tid * 4; idx < 8192; idx += 1024)
        *(s16x4*)(dst + idx) = *(const s16x4*)(wt + idx);
}

// ---------------------------------------------------------------------------
// SA: stream adj, 4x batched issue per 1024-col super-iteration; per 4 cols
// one adj i32x4 + one table u32x4 (4 B/col). Branch: e1 >= T (T=exp(-a1)).
// Bit layout: col j -> word (j>>8)*8 + ((j>>7)&1)*4 + (j&3), bit (j>>2)&31.
// ---------------------------------------------------------------------------
static __device__ inline void sa_group(const i32x4 v, const u32x4 tb,
                                       const float T, const int lane,
                                       float& s1, float& s2,
                                       unsigned* __restrict__ bgrp) {
    unsigned long long m0 = __ballot(v.x != 0);
    unsigned long long m1 = __ballot(v.y != 0);
    unsigned long long m2 = __ballot(v.z != 0);
    unsigned long long m3 = __ballot(v.w != 0);
    if (lane == 0) {
        u32x4 w;
        w.x = (unsigned)m0; w.y = (unsigned)m1;
        w.z = (unsigned)m2; w.w = (unsigned)m3;
        *(u32x4*)(bgrp) = w;
    } else if (lane == 32) {
        u32x4 w;
        w.x = (unsigned)(m0 >> 32); w.y = (unsigned)(m1 >> 32);
        w.z = (unsigned)(m2 >> 32); w.w = (unsigned)(m3 >> 32);
        *(u32x4*)(bgrp + 4) = w;
    }
    float e1, e2; bool px;
    e1 = __uint_as_float(tb.x << 16); e2 = __uint_as_float(tb.x & 0xffff0000u);
    px = (e1 >= T);
    s1 += (v.x && px) ? e1 : 0.f;  s2 += (v.x && !px) ? e2 : 0.f;
    e1 = __uint_as_float(tb.y << 16); e2 = __uint_as_float(tb.y & 0xffff0000u);
    px = (e1 >= T);
    s1 += (v.y && px) ? e1 : 0.f;  s2 += (v.y && !px) ? e2 : 0.f;
    e1 = __uint_as_float(tb.z << 16); e2 = __uint_as_float(tb.z & 0xffff0000u);
    px = (e1 >= T);
    s1 += (v.z && px) ? e1 : 0.f;  s2 += (v.z && !px) ? e2 : 0.f;
    e1 = __uint_as_float(tb.w << 16); e2 = __uint_as_float(tb.w & 0xffff0000u);
    px = (e1 >= T);
    s1 += (v.w && px) ? e1 : 0.f;  s2 += (v.w && !px) ? e2 : 0.f;
}

__global__ __launch_bounds__(256) void sa_scan(const int* __restrict__ adj,
                                               const float* __restrict__ a1g,
                                               const unsigned* __restrict__ pku,
                                               unsigned* __restrict__ bm,
                                               float* __restrict__ crow) {
    const int wid = threadIdx.x >> 6, lane = threadIdx.x & 63;
    const int i = blockIdx.x * 4 + wid;
    const float a1i = a1g[i];
    const float T = expf(-a1i);
    const int* arow = adj + (size_t)i * NN;
    unsigned* brow = bm + (size_t)i * (NN / 32);

    float s1 = 0.f, s2 = 0.f;
    for (int it = 0; it < NN / 1024; ++it) {
        const int j0 = it * 1024 + lane * 4;
        i32x4 v0 = __builtin_nontemporal_load((const i32x4*)(arow + j0));
        i32x4 v1 = __builtin_nontemporal_load((const i32x4*)(arow + j0 + 256));
        i32x4 v2 = __builtin_nontemporal_load((const i32x4*)(arow + j0 + 512));
        i32x4 v3 = __builtin_nontemporal_load((const i32x4*)(arow + j0 + 768));
        u32x4 t0 = *(const u32x4*)(pku + j0);
        u32x4 t1 = *(const u32x4*)(pku + j0 + 256);
        u32x4 t2 = *(const u32x4*)(pku + j0 + 512);
        u32x4 t3 = *(const u32x4*)(pku + j0 + 768);
        unsigned* bsup = brow + it * 32;
        sa_group(v0, t0, T, lane, s1, s2, bsup);
        sa_group(v1, t1, T, lane, s1, s2, bsup + 8);
        sa_group(v2, t2, T, lane, s1, s2, bsup + 16);
        sa_group(v3, t3, T, lane, s1, s2, bsup + 24);
    }
    #pragma unroll
    for (int o = 32; o >= 1; o >>= 1) {
        s1 += __shfl_xor(s1, o, 64);
        s2 += __shfl_xor(s2, o, 64);
    }
    if (lane == 0) {
        float c1 = 0.f, c2 = 0.f;
        if (s1 + s2 > 0.f) {
            float e1v = expf(a1i);
            float e2v = expf(0.2f * a1i);
            float S = e1v * s1 + e2v * s2;
            c1 = e1v / S;
            c2 = e2v / S;
        }
        crow[i * 4 + 0] = c1;
        crow[i * 4 + 1] = c2;
        crow[i * 4 + 2] = T;
        crow[i * 4 + 3] = 0.f;
    }
}

// ---------------------------------------------------------------------------
// SB: fused alpha-write + PV MFMA, split-K (exact r11 champion structure;
// table gather halved to one u32x4 per thread per chunk). grid (NN/64, 8),
// 512 threads, <=64 VGPR, LDS = abuf only -> 4 blocks/CU.
// ---------------------------------------------------------------------------
__global__ __launch_bounds__(512, 8) void sb_pv(const unsigned* __restrict__ bm,
                                                const float* __restrict__ crowG,
                                                const unsigned* __restrict__ pku,
                                                const __hip_bfloat16* __restrict__ whbT,
                                                float* __restrict__ alpha,
                                                float* __restrict__ part) {
    __shared__ __hip_bfloat16 abuf[2][RPB][KC + 8];      // 34.8 KB (sole LDS)

    const int tid = threadIdx.x;
    const int wv = tid >> 6, lane = tid & 63;
    const int r0 = blockIdx.x * RPB;
    const int ks = blockIdx.y;
    const int k0 = ks * KSL;

    const int rloc = tid >> 5;
    float c1r[4], c2r[4], Tr[4];
    #pragma unroll
    for (int v = 0; v < 4; ++v) {
        f32x4 cw = *(const f32x4*)(crowG + (size_t)(r0 + rloc + 16 * v) * 4);
        c1r[v] = cw.x; c2r[v] = cw.y; Tr[v] = cw.z;
    }

    f32x4 acc[4];
    #pragma unroll
    for (int rt = 0; rt < 4; ++rt) acc[rt] = (f32x4){0.f, 0.f, 0.f, 0.f};
    const int n0 = wv * 16;
    const short* wb = reinterpret_cast<const short*>(whbT);
    const short* bbase = wb + (size_t)(n0 + (lane & 15)) * 8 + (size_t)(lane >> 4) * 1024;

    const int cgrp = (tid & 31) << 2;
    const unsigned pbit = tid & 31;

    for (int kc = 0; kc < KSL; kc += KC) {
        const int dbuf = (kc >> 7) & 1;
        const int jl = kc + cgrp;
        const int j = k0 + jl;
        const int wbw = ((jl >> 8) << 3) + (((jl >> 7) & 1) << 2);
        u32x4 tb = *(const u32x4*)(pku + j);
        float e1c[4], e2c[4];
        e1c[0] = __uint_as_float(tb.x << 16); e2c[0] = __uint_as_float(tb.x & 0xffff0000u);
        e1c[1] = __uint_as_float(tb.y << 16); e2c[1] = __uint_as_float(tb.y & 0xffff0000u);
        e1c[2] = __uint_as_float(tb.z << 16); e2c[2] = __uint_as_float(tb.z & 0xffff0000u);
        e1c[3] = __uint_as_float(tb.w << 16); e2c[3] = __uint_as_float(tb.w & 0xffff0000u);
        #pragma unroll
        for (int v = 0; v < 4; ++v) {
            const int r = rloc + 16 * v;
            const int gr = r0 + r;
            u32x4 w4 = *(const u32x4*)(bm + (size_t)gr * (NN / 32) + ks * (KSL / 32) + wbw);
            const float c1 = c1r[v], c2 = c2r[v], T = Tr[v];
            f32x4 al;
            al.x = ((w4.x >> pbit) & 1) ? ((e1c[0] >= T) ? c1 * e1c[0] : c2 * e2c[0]) : 0.f;
            al.y = ((w4.y >> pbit) & 1) ? ((e1c[1] >= T) ? c1 * e1c[1] : c2 * e2c[1]) : 0.f;
            al.z = ((w4.z >> pbit) & 1) ? ((e1c[2] >= T) ? c1 * e1c[2] : c2 * e2c[2]) : 0.f;
            al.w = ((w4.w >> pbit) & 1) ? ((e1c[3] >= T) ? c1 * e1c[3] : c2 * e2c[3]) : 0.f;
            __builtin_nontemporal_store(al, (f32x4*)(alpha + (size_t)gr * NN + j));
            u16x4 ub4;
            ub4.x = f2bf(al.x); ub4.y = f2bf(al.y); ub4.z = f2bf(al.z); ub4.w = f2bf(al.w);
            *(u16x4*)(&abuf[dbuf][r][cgrp]) = ub4;
        }
        __syncthreads();
        #pragma unroll
        for (int kk = 0; kk < KC; kk += 32) {
            bf16x8 bf = *(const bf16x8*)(bbase + (size_t)((k0 + kc + kk) >> 3) * 1024);
            #pragma unroll
            for (int rt = 0; rt < 4; ++rt) {
                bf16x8 af = *(const bf16x8*)(&abuf[dbuf][rt * 16 + (lane & 15)][kk + 8 * (lane >> 4)]);
                acc[rt] = __builtin_amdgcn_mfma_f32_16x16x32_bf16(af, bf, acc[rt], 0, 0, 0);
            }
        }
    }

    float* pb2 = part + (size_t)ks * NN * DIM;
    const int rb = (lane >> 4) * 4;
    #pragma unroll
    for (int rt = 0; rt < 4; ++rt) {
        #pragma unroll
        for (int q = 0; q < 4; ++q)
            pb2[(size_t)(r0 + rt * 16 + rb + q) * DIM + n0 + (lane & 15)] = acc[rt][q];
    }
}

// ---------------------------------------------------------------------------
// K5: reduce split-K partials -> out (vectorized; part is L2-warm)
// ---------------------------------------------------------------------------
__global__ __launch_bounds__(256) void k5_reduce(const float* __restrict__ part,
                                                 float* __restrict__ out) {
    const size_t idx = ((size_t)blockIdx.x * 256 + threadIdx.x) * 4;
    f32x4 s = (f32x4){0.f, 0.f, 0.f, 0.f};
    #pragma unroll
    for (int ks = 0; ks < KS; ++ks)
        s += *(const f32x4*)(part + (size_t)ks * NN * DIM + idx);
    *(f32x4*)(out + idx) = s;
}

// ---------------------------------------------------------------------------
extern "C" void kernel_launch(void* const* d_in, const int* in_sizes, int n_in,
                              void* d_out, int out_size, void* d_ws, size_t ws_size,
                              hipStream_t stream) {
    const float* h   = (const float*)d_in[0];
    const int*   adj = (const int*)d_in[1];
    const float* W   = (const float*)d_in[2];
    const float* a   = (const float*)d_in[3];

    float* out   = (float*)d_out;
    float* alpha = out + (size_t)NN * DIM;

    char* ws = (char*)d_ws;
    __hip_bfloat16* whbT = (__hip_bfloat16*)(ws);          // 2 MB
    float* a1g    = (float*)(ws + 0x200000);               // 32 KB
    unsigned* pku = (unsigned*)(ws + 0x208000);            // 32 KB
    float* crow   = (float*)(ws + 0x218000);               // 128 KB
    unsigned* bm  = (unsigned*)(ws + 0x240000);            // 8 MB
    float* part   = (float*)(ws + 0xA40000);               // KS*4 MB = 32 MB

    k1m<<<NN / 64, 256, 0, stream>>>(h, W, a, whbT, a1g, pku);
    sa_scan<<<NN / 4, 256, 0, stream>>>(adj, a1g, pku, bm, crow);
    sb_pv<<<dim3(NN / RPB, KS), 512, 0, stream>>>(bm, crow, pku, whbT, alpha, part);
    k5_reduce<<<NN * DIM / 1024, 256, 0, stream>>>(part, out);
}

// Round 15
// 161.182 us; speedup vs baseline: 1.1014x; 1.0020x over previous
//
#include <hip/hip_runtime.h>
#include <hip/hip_bf16.h>

#define NN 8192
#define DIM 128
#define KS 8            // split-K factor for PV
#define KSL (NN / KS)   // 1024 k per slice
#define RPB 64          // rows per SB block
#define KC 128          // k-chunk width in SB

typedef __attribute__((ext_vector_type(8))) short bf16x8;
typedef __attribute__((ext_vector_type(4))) float f32x4;
typedef __attribute__((ext_vector_type(4))) int i32x4;
typedef __attribute__((ext_vector_type(4))) unsigned int u32x4;
typedef __attribute__((ext_vector_type(4))) unsigned short u16x4;
typedef __attribute__((ext_vector_type(4))) short s16x4;

static __device__ inline unsigned short f2bf(float x) {
    __hip_bfloat16 b = __float2bfloat16(x);
    return *reinterpret_cast<unsigned short*>(&b);
}

struct BSplit { short hi, lo; };
static __device__ inline BSplit bsplit(float x) {
    BSplit r;
    __hip_bfloat16 h = __float2bfloat16(x);
    r.hi = *reinterpret_cast<short*>(&h);
    float rem = x - __bfloat162float(h);
    __hip_bfloat16 l = __float2bfloat16(rem);
    r.lo = *reinterpret_cast<short*>(&l);
    return r;
}

// ---------------------------------------------------------------------------
// K1M: Wh = h@W^T (split-bf16 MFMA, f32-grade), a1 (f32), packed table
// pku[j] = bf16(E1)|bf16(E2)<<16 (4 B/col — leaky branch test a1+a2>=0 is
// equivalent to E1 >= exp(-a1)), and whbT (bf16, tiled [k>>3][dim][k&7]).
// grid 128 x 64 rows, 4 waves.
// ---------------------------------------------------------------------------
__global__ __launch_bounds__(256) void k1m(const float* __restrict__ h,
                                           const float* __restrict__ W,
                                           const float* __restrict__ a,
                                           __hip_bfloat16* __restrict__ whbT,
                                           float* __restrict__ a1g,
                                           unsigned* __restrict__ pku) {
    __shared__ short whi[128 * 132];         // W hi, row stride 132 (264B)
    __shared__ short wlo[128 * 132];         // W lo
    __shared__ short wt[8 * 128 * 8];        // whbT retile staging (16 KB)
    __shared__ float a_sh[256];

    const int tid = threadIdx.x;
    const int wv = tid >> 6, lane = tid & 63;
    const int r0 = blockIdx.x * 64;

    for (int idx = tid; idx < 128 * 128; idx += 256) {
        const int d = idx >> 7, k = idx & 127;
        BSplit s = bsplit(W[idx]);
        whi[d * 132 + k] = s.hi;
        wlo[d * 132 + k] = s.lo;
    }
    a_sh[tid] = a[tid];
    __syncthreads();

    f32x4 acc[8];
    #pragma unroll
    for (int n = 0; n < 8; ++n) acc[n] = (f32x4){0.f, 0.f, 0.f, 0.f};

    const int arow = r0 + wv * 16 + (lane & 15);
    const int ksub = (lane >> 4) * 8;
    const float* hp = h + (size_t)arow * DIM + ksub;

    #pragma unroll
    for (int kk = 0; kk < 128; kk += 32) {
        f32x4 x0 = *(const f32x4*)(hp + kk);
        f32x4 x1 = *(const f32x4*)(hp + kk + 4);
        bf16x8 ah, al;
        {
            BSplit s0 = bsplit(x0.x), s1 = bsplit(x0.y), s2 = bsplit(x0.z), s3 = bsplit(x0.w);
            BSplit s4 = bsplit(x1.x), s5 = bsplit(x1.y), s6 = bsplit(x1.z), s7 = bsplit(x1.w);
            ah[0] = s0.hi; al[0] = s0.lo; ah[1] = s1.hi; al[1] = s1.lo;
            ah[2] = s2.hi; al[2] = s2.lo; ah[3] = s3.hi; al[3] = s3.lo;
            ah[4] = s4.hi; al[4] = s4.lo; ah[5] = s5.hi; al[5] = s5.lo;
            ah[6] = s6.hi; al[6] = s6.lo; ah[7] = s7.hi; al[7] = s7.lo;
        }
        #pragma unroll
        for (int n = 0; n < 8; ++n) {
            const int boff = (n * 16 + (lane & 15)) * 132 + kk + ksub;
            bf16x8 bh = *(const bf16x8*)(whi + boff);
            bf16x8 bl = *(const bf16x8*)(wlo + boff);
            acc[n] = __builtin_amdgcn_mfma_f32_16x16x32_bf16(ah, bh, acc[n], 0, 0, 0);
            acc[n] = __builtin_amdgcn_mfma_f32_16x16x32_bf16(ah, bl, acc[n], 0, 0, 0);
            acc[n] = __builtin_amdgcn_mfma_f32_16x16x32_bf16(al, bh, acc[n], 0, 0, 0);
        }
    }

    float p1[4] = {0.f, 0.f, 0.f, 0.f}, p2[4] = {0.f, 0.f, 0.f, 0.f};
    #pragma unroll
    for (int n = 0; n < 8; ++n) {
        const float av1 = a_sh[n * 16 + (lane & 15)];
        const float av2 = a_sh[128 + n * 16 + (lane & 15)];
        #pragma unroll
        for (int q = 0; q < 4; ++q) {
            p1[q] += acc[n][q] * av1;
            p2[q] += acc[n][q] * av2;
        }
    }
    #pragma unroll
    for (int o = 8; o >= 1; o >>= 1) {
        #pragma unroll
        for (int q = 0; q < 4; ++q) {
            p1[q] += __shfl_xor(p1[q], o, 64);
            p2[q] += __shfl_xor(p2[q], o, 64);
        }
    }
    if ((lane & 15) == 0) {
        #pragma unroll
        for (int q = 0; q < 4; ++q) {
            const int row = r0 + wv * 16 + (lane >> 4) * 4 + q;
            a1g[row] = p1[q];
            const float E1v = expf(p2[q]);
            const float E2v = expf(0.2f * p2[q]);
            pku[row] = (unsigned)f2bf(E1v) | ((unsigned)f2bf(E2v) << 16);
        }
    }

    #pragma unroll
    for (int n = 0; n < 8; ++n) {
        #pragma unroll
        for (int q = 0; q < 4; ++q) {
            const int kloc = wv * 16 + (lane >> 4) * 4 + q;   // block-local k
            const int d = n * 16 + (lane & 15);
            wt[(kloc >> 3) * 1024 + d * 8 + (kloc & 7)] = (short)f2bf(acc[n][q]);
        }
    }
    __syncthreads();
    short* dst = reinterpret_cast<short*>(whbT) + ((size_t)r0 << 7);
    for (int idx = tid * 4; idx < 8192; idx += 1024)
        *(s16x4*)(dst + idx) = *(const s16x4*)(wt + idx);
}

// ---------------------------------------------------------------------------
// SA: stream adj, 4x batched issue per 1024-col super-iteration; per 4 cols
// one adj i32x4 + one table u32x4 (4 B/col). Branch: e1 >= T (T=exp(-a1)).
// Bit layout: col j -> word (j>>8)*8 + ((j>>7)&1)*4 + (j&3), bit (j>>2)&31.
// ---------------------------------------------------------------------------
static __device__ inline void sa_group(const i32x4 v, const u32x4 tb,
                                       const float T, const int lane,
                                       float& s1, float& s2,
                                       unsigned* __restrict__ bgrp) {
    unsigned long long m0 = __ballot(v.x != 0);
    unsigned long long m1 = __ballot(v.y != 0);
    unsigned long long m2 = __ballot(v.z != 0);
    unsigned long long m3 = __ballot(v.w != 0);
    if (lane == 0) {
        u32x4 w;
        w.x = (unsigned)m0; w.y = (unsigned)m1;
        w.z = (unsigned)m2; w.w = (unsigned)m3;
        *(u32x4*)(bgrp) = w;
    } else if (lane == 32) {
        u32x4 w;
        w.x = (unsigned)(m0 >> 32); w.y = (unsigned)(m1 >> 32);
        w.z = (unsigned)(m2 >> 32); w.w = (unsigned)(m3 >> 32);
        *(u32x4*)(bgrp + 4) = w;
    }
    float e1, e2; bool px;
    e1 = __uint_as_float(tb.x << 16); e2 = __uint_as_float(tb.x & 0xffff0000u);
    px = (e1 >= T);
    s1 += (v.x && px) ? e1 : 0.f;  s2 += (v.x && !px) ? e2 : 0.f;
    e1 = __uint_as_float(tb.y << 16); e2 = __uint_as_float(tb.y & 0xffff0000u);
    px = (e1 >= T);
    s1 += (v.y && px) ? e1 : 0.f;  s2 += (v.y && !px) ? e2 : 0.f;
    e1 = __uint_as_float(tb.z << 16); e2 = __uint_as_float(tb.z & 0xffff0000u);
    px = (e1 >= T);
    s1 += (v.z && px) ? e1 : 0.f;  s2 += (v.z && !px) ? e2 : 0.f;
    e1 = __uint_as_float(tb.w << 16); e2 = __uint_as_float(tb.w & 0xffff0000u);
    px = (e1 >= T);
    s1 += (v.w && px) ? e1 : 0.f;  s2 += (v.w && !px) ? e2 : 0.f;
}

__global__ __launch_bounds__(256) void sa_scan(const int* __restrict__ adj,
                                               const float* __restrict__ a1g,
                                               const unsigned* __restrict__ pku,
                                               unsigned* __restrict__ bm,
                                               float* __restrict__ crow) {
    const int wid = threadIdx.x >> 6, lane = threadIdx.x & 63;
    const int i = blockIdx.x * 4 + wid;
    const float a1i = a1g[i];
    const float T = expf(-a1i);
    const int* arow = adj + (size_t)i * NN;
    unsigned* brow = bm + (size_t)i * (NN / 32);

    float s1 = 0.f, s2 = 0.f;
    for (int it = 0; it < NN / 1024; ++it) {
        const int j0 = it * 1024 + lane * 4;
        i32x4 v0 = __builtin_nontemporal_load((const i32x4*)(arow + j0));
        i32x4 v1 = __builtin_nontemporal_load((const i32x4*)(arow + j0 + 256));
        i32x4 v2 = __builtin_nontemporal_load((const i32x4*)(arow + j0 + 512));
        i32x4 v3 = __builtin_nontemporal_load((const i32x4*)(arow + j0 + 768));
        u32x4 t0 = *(const u32x4*)(pku + j0);
        u32x4 t1 = *(const u32x4*)(pku + j0 + 256);
        u32x4 t2 = *(const u32x4*)(pku + j0 + 512);
        u32x4 t3 = *(const u32x4*)(pku + j0 + 768);
        unsigned* bsup = brow + it * 32;
        sa_group(v0, t0, T, lane, s1, s2, bsup);
        sa_group(v1, t1, T, lane, s1, s2, bsup + 8);
        sa_group(v2, t2, T, lane, s1, s2, bsup + 16);
        sa_group(v3, t3, T, lane, s1, s2, bsup + 24);
    }
    #pragma unroll
    for (int o = 32; o >= 1; o >>= 1) {
        s1 += __shfl_xor(s1, o, 64);
        s2 += __shfl_xor(s2, o, 64);
    }
    if (lane == 0) {
        float c1 = 0.f, c2 = 0.f;
        if (s1 + s2 > 0.f) {
            float e1v = expf(a1i);
            float e2v = expf(0.2f * a1i);
            float S = e1v * s1 + e2v * s2;
            c1 = e1v / S;
            c2 = e2v / S;
        }
        crow[i * 4 + 0] = c1;
        crow[i * 4 + 1] = c2;
        crow[i * 4 + 2] = T;
        crow[i * 4 + 3] = 0.f;
    }
}

// ---------------------------------------------------------------------------
// SB: fused alpha-write + PV MFMA, split-K. grid (NN/64, 8), 512 threads,
// <=64 VGPR, LDS = abuf only -> 4 blocks/CU.
// MFMA-phase remap vs r14: each wave owns 32 rows x 32 dims (rt2 = wv&1,
// dim-quarter = wv>>1) -> LDS A-frag reads HALVED (8 ds_read_b128/wave/chunk,
// was 16: every wave was re-reading all 64 rows); B-frag loads double but
// whbT (2 MB) is L2-resident. acc stays 16 VGPR; write phase unchanged.
// ---------------------------------------------------------------------------
__global__ __launch_bounds__(512, 8) void sb_pv(const unsigned* __restrict__ bm,
                                                const float* __restrict__ crowG,
                                                const unsigned* __restrict__ pku,
                                                const __hip_bfloat16* __restrict__ whbT,
                                                float* __restrict__ alpha,
                                                float* __restrict__ part) {
    __shared__ __hip_bfloat16 abuf[2][RPB][KC + 8];      // 34.8 KB (sole LDS)

    const int tid = threadIdx.x;
    const int wv = tid >> 6, lane = tid & 63;
    const int r0 = blockIdx.x * RPB;
    const int ks = blockIdx.y;
    const int k0 = ks * KSL;

    const int rloc = tid >> 5;
    float c1r[4], c2r[4], Tr[4];
    #pragma unroll
    for (int v = 0; v < 4; ++v) {
        f32x4 cw = *(const f32x4*)(crowG + (size_t)(r0 + rloc + 16 * v) * 4);
        c1r[v] = cw.x; c2r[v] = cw.y; Tr[v] = cw.z;
    }

    // MFMA-phase ownership: 32 rows x 32 dims per wave
    const int rt2 = wv & 1;              // row half (rows rt2*32 .. rt2*32+31)
    const int n0 = (wv >> 1) * 32;       // dim quarter
    f32x4 acc[2][2];
    #pragma unroll
    for (int rp = 0; rp < 2; ++rp)
        #pragma unroll
        for (int nn = 0; nn < 2; ++nn)
            acc[rp][nn] = (f32x4){0.f, 0.f, 0.f, 0.f};

    const short* wb = reinterpret_cast<const short*>(whbT);
    const short* bbase = wb + (size_t)(n0 + (lane & 15)) * 8 + (size_t)(lane >> 4) * 1024;

    const int cgrp = (tid & 31) << 2;
    const unsigned pbit = tid & 31;

    for (int kc = 0; kc < KSL; kc += KC) {
        const int dbuf = (kc >> 7) & 1;
        const int jl = kc + cgrp;
        const int j = k0 + jl;
        const int wbw = ((jl >> 8) << 3) + (((jl >> 7) & 1) << 2);
        u32x4 tb = *(const u32x4*)(pku + j);
        float e1c[4], e2c[4];
        e1c[0] = __uint_as_float(tb.x << 16); e2c[0] = __uint_as_float(tb.x & 0xffff0000u);
        e1c[1] = __uint_as_float(tb.y << 16); e2c[1] = __uint_as_float(tb.y & 0xffff0000u);
        e1c[2] = __uint_as_float(tb.z << 16); e2c[2] = __uint_as_float(tb.z & 0xffff0000u);
        e1c[3] = __uint_as_float(tb.w << 16); e2c[3] = __uint_as_float(tb.w & 0xffff0000u);
        #pragma unroll
        for (int v = 0; v < 4; ++v) {
            const int r = rloc + 16 * v;
            const int gr = r0 + r;
            u32x4 w4 = *(const u32x4*)(bm + (size_t)gr * (NN / 32) + ks * (KSL / 32) + wbw);
            const float c1 = c1r[v], c2 = c2r[v], T = Tr[v];
            f32x4 al;
            al.x = ((w4.x >> pbit) & 1) ? ((e1c[0] >= T) ? c1 * e1c[0] : c2 * e2c[0]) : 0.f;
            al.y = ((w4.y >> pbit) & 1) ? ((e1c[1] >= T) ? c1 * e1c[1] : c2 * e2c[1]) : 0.f;
            al.z = ((w4.z >> pbit) & 1) ? ((e1c[2] >= T) ? c1 * e1c[2] : c2 * e2c[2]) : 0.f;
            al.w = ((w4.w >> pbit) & 1) ? ((e1c[3] >= T) ? c1 * e1c[3] : c2 * e2c[3]) : 0.f;
            __builtin_nontemporal_store(al, (f32x4*)(alpha + (size_t)gr * NN + j));
            u16x4 ub4;
            ub4.x = f2bf(al.x); ub4.y = f2bf(al.y); ub4.z = f2bf(al.z); ub4.w = f2bf(al.w);
            *(u16x4*)(&abuf[dbuf][r][cgrp]) = ub4;
        }
        __syncthreads();
        #pragma unroll
        for (int kk = 0; kk < KC; kk += 32) {
            const short* bp = bbase + (size_t)((k0 + kc + kk) >> 3) * 1024;
            bf16x8 b0 = *(const bf16x8*)(bp);
            bf16x8 b1 = *(const bf16x8*)(bp + 128);      // +16 dims
            #pragma unroll
            for (int rp = 0; rp < 2; ++rp) {
                bf16x8 af = *(const bf16x8*)(&abuf[dbuf][rt2 * 32 + rp * 16 + (lane & 15)]
                                                   [kk + 8 * (lane >> 4)]);
                acc[rp][0] = __builtin_amdgcn_mfma_f32_16x16x32_bf16(af, b0, acc[rp][0], 0, 0, 0);
                acc[rp][1] = __builtin_amdgcn_mfma_f32_16x16x32_bf16(af, b1, acc[rp][1], 0, 0, 0);
            }
        }
    }

    float* pb2 = part + (size_t)ks * NN * DIM;
    const int rb = (lane >> 4) * 4;
    #pragma unroll
    for (int rp = 0; rp < 2; ++rp) {
        #pragma unroll
        for (int nn = 0; nn < 2; ++nn) {
            #pragma unroll
            for (int q = 0; q < 4; ++q)
                pb2[(size_t)(r0 + rt2 * 32 + rp * 16 + rb + q) * DIM
                    + n0 + nn * 16 + (lane & 15)] = acc[rp][nn][q];
        }
    }
}

// ---------------------------------------------------------------------------
// K5: reduce split-K partials -> out (vectorized; part is L2-warm)
// ---------------------------------------------------------------------------
__global__ __launch_bounds__(256) void k5_reduce(const float* __restrict__ part,
                                                 float* __restrict__ out) {
    const size_t idx = ((size_t)blockIdx.x * 256 + threadIdx.x) * 4;
    f32x4 s = (f32x4){0.f, 0.f, 0.f, 0.f};
    #pragma unroll
    for (int ks = 0; ks < KS; ++ks)
        s += *(const f32x4*)(part + (size_t)ks * NN * DIM + idx);
    *(f32x4*)(out + idx) = s;
}

// ---------------------------------------------------------------------------
extern "C" void kernel_launch(void* const* d_in, const int* in_sizes, int n_in,
                              void* d_out, int out_size, void* d_ws, size_t ws_size,
                              hipStream_t stream) {
    const float* h   = (const float*)d_in[0];
    const int*   adj = (const int*)d_in[1];
    const float* W   = (const float*)d_in[2];
    const float* a   = (const float*)d_in[3];

    float* out   = (float*)d_out;
    float* alpha = out + (size_t)NN * DIM;

    char* ws = (char*)d_ws;
    __hip_bfloat16* whbT = (__hip_bfloat16*)(ws);          // 2 MB
    float* a1g    = (float*)(ws + 0x200000);               // 32 KB
    unsigned* pku = (unsigned*)(ws + 0x208000);            // 32 KB
    float* crow   = (float*)(ws + 0x218000);               // 128 KB
    unsigned* bm  = (unsigned*)(ws + 0x240000);            // 8 MB
    float* part   = (float*)(ws + 0xA40000);               // KS*4 MB = 32 MB

    k1m<<<NN / 64, 256, 0, stream>>>(h, W, a, whbT, a1g, pku);
    sa_scan<<<NN / 4, 256, 0, stream>>>(adj, a1g, pku, bm, crow);
    sb_pv<<<dim3(NN / RPB, KS), 512, 0, stream>>>(bm, crow, pku, whbT, alpha, part);
    k5_reduce<<<NN * DIM / 1024, 256, 0, stream>>>(part, out);
}

// Round 16
// 157.383 us; speedup vs baseline: 1.1279x; 1.0241x over previous
//
#include <hip/hip_runtime.h>
#include <hip/hip_bf16.h>

#define NN 8192
#define DIM 128
#define KS 8            // split-K factor for PV
#define KSL (NN / KS)   // 1024 k per slice
#define RPB 64          // rows per SB block
#define KC 128          // k-chunk width in SB

typedef __attribute__((ext_vector_type(8))) short bf16x8;
typedef __attribute__((ext_vector_type(4))) float f32x4;
typedef __attribute__((ext_vector_type(4))) int i32x4;
typedef __attribute__((ext_vector_type(4))) unsigned int u32x4;
typedef __attribute__((ext_vector_type(4))) unsigned short u16x4;
typedef __attribute__((ext_vector_type(4))) short s16x4;

static __device__ inline unsigned short f2bf(float x) {
    __hip_bfloat16 b = __float2bfloat16(x);
    return *reinterpret_cast<unsigned short*>(&b);
}

struct BSplit { short hi, lo; };
static __device__ inline BSplit bsplit(float x) {
    BSplit r;
    __hip_bfloat16 h = __float2bfloat16(x);
    r.hi = *reinterpret_cast<short*>(&h);
    float rem = x - __bfloat162float(h);
    __hip_bfloat16 l = __float2bfloat16(rem);
    r.lo = *reinterpret_cast<short*>(&l);
    return r;
}

// ---------------------------------------------------------------------------
// K1M: Wh = h@W^T (split-bf16 MFMA, f32-grade), a1 (f32), packed table
// pku[j] = bf16(E1)|bf16(E2)<<16 (4 B/col — leaky branch test a1+a2>=0 is
// equivalent to E1 >= exp(-a1)), and whbT (bf16, tiled [k>>3][dim][k&7]).
// grid 128 x 64 rows, 4 waves.
// ---------------------------------------------------------------------------
__global__ __launch_bounds__(256) void k1m(const float* __restrict__ h,
                                           const float* __restrict__ W,
                                           const float* __restrict__ a,
                                           __hip_bfloat16* __restrict__ whbT,
                                           float* __restrict__ a1g,
                                           unsigned* __restrict__ pku) {
    __shared__ short whi[128 * 132];         // W hi, row stride 132 (264B)
    __shared__ short wlo[128 * 132];         // W lo
    __shared__ short wt[8 * 128 * 8];        // whbT retile staging (16 KB)
    __shared__ float a_sh[256];

    const int tid = threadIdx.x;
    const int wv = tid >> 6, lane = tid & 63;
    const int r0 = blockIdx.x * 64;

    for (int idx = tid; idx < 128 * 128; idx += 256) {
        const int d = idx >> 7, k = idx & 127;
        BSplit s = bsplit(W[idx]);
        whi[d * 132 + k] = s.hi;
        wlo[d * 132 + k] = s.lo;
    }
    a_sh[tid] = a[tid];
    __syncthreads();

    f32x4 acc[8];
    #pragma unroll
    for (int n = 0; n < 8; ++n) acc[n] = (f32x4){0.f, 0.f, 0.f, 0.f};

    const int arow = r0 + wv * 16 + (lane & 15);
    const int ksub = (lane >> 4) * 8;
    const float* hp = h + (size_t)arow * DIM + ksub;

    #pragma unroll
    for (int kk = 0; kk < 128; kk += 32) {
        f32x4 x0 = *(const f32x4*)(hp + kk);
        f32x4 x1 = *(const f32x4*)(hp + kk + 4);
        bf16x8 ah, al;
        {
            BSplit s0 = bsplit(x0.x), s1 = bsplit(x0.y), s2 = bsplit(x0.z), s3 = bsplit(x0.w);
            BSplit s4 = bsplit(x1.x), s5 = bsplit(x1.y), s6 = bsplit(x1.z), s7 = bsplit(x1.w);
            ah[0] = s0.hi; al[0] = s0.lo; ah[1] = s1.hi; al[1] = s1.lo;
            ah[2] = s2.hi; al[2] = s2.lo; ah[3] = s3.hi; al[3] = s3.lo;
            ah[4] = s4.hi; al[4] = s4.lo; ah[5] = s5.hi; al[5] = s5.lo;
            ah[6] = s6.hi; al[6] = s6.lo; ah[7] = s7.hi; al[7] = s7.lo;
        }
        #pragma unroll
        for (int n = 0; n < 8; ++n) {
            const int boff = (n * 16 + (lane & 15)) * 132 + kk + ksub;
            bf16x8 bh = *(const bf16x8*)(whi + boff);
            bf16x8 bl = *(const bf16x8*)(wlo + boff);
            acc[n] = __builtin_amdgcn_mfma_f32_16x16x32_bf16(ah, bh, acc[n], 0, 0, 0);
            acc[n] = __builtin_amdgcn_mfma_f32_16x16x32_bf16(ah, bl, acc[n], 0, 0, 0);
            acc[n] = __builtin_amdgcn_mfma_f32_16x16x32_bf16(al, bh, acc[n], 0, 0, 0);
        }
    }

    float p1[4] = {0.f, 0.f, 0.f, 0.f}, p2[4] = {0.f, 0.f, 0.f, 0.f};
    #pragma unroll
    for (int n = 0; n < 8; ++n) {
        const float av1 = a_sh[n * 16 + (lane & 15)];
        const float av2 = a_sh[128 + n * 16 + (lane & 15)];
        #pragma unroll
        for (int q = 0; q < 4; ++q) {
            p1[q] += acc[n][q] * av1;
            p2[q] += acc[n][q] * av2;
        }
    }
    #pragma unroll
    for (int o = 8; o >= 1; o >>= 1) {
        #pragma unroll
        for (int q = 0; q < 4; ++q) {
            p1[q] += __shfl_xor(p1[q], o, 64);
            p2[q] += __shfl_xor(p2[q], o, 64);
        }
    }
    if ((lane & 15) == 0) {
        #pragma unroll
        for (int q = 0; q < 4; ++q) {
            const int row = r0 + wv * 16 + (lane >> 4) * 4 + q;
            a1g[row] = p1[q];
            const float E1v = expf(p2[q]);
            const float E2v = expf(0.2f * p2[q]);
            pku[row] = (unsigned)f2bf(E1v) | ((unsigned)f2bf(E2v) << 16);
        }
    }

    #pragma unroll
    for (int n = 0; n < 8; ++n) {
        #pragma unroll
        for (int q = 0; q < 4; ++q) {
            const int kloc = wv * 16 + (lane >> 4) * 4 + q;   // block-local k
            const int d = n * 16 + (lane & 15);
            wt[(kloc >> 3) * 1024 + d * 8 + (kloc & 7)] = (short)f2bf(acc[n][q]);
        }
    }
    __syncthreads();
    short* dst = reinterpret_cast<short*>(whbT) + ((size_t)r0 << 7);
    for (int idx = tid * 4; idx < 8192; idx += 1024)
        *(s16x4*)(dst + idx) = *(const s16x4*)(wt + idx);
}

// ---------------------------------------------------------------------------
// SA: stream adj, 4x batched issue per 1024-col super-iteration; per 4 cols
// one adj i32x4 + one table u32x4 (4 B/col). Branch: e1 >= T (T=exp(-a1)).
// Bit layout: col j -> word (j>>8)*8 + ((j>>7)&1)*4 + (j&3), bit (j>>2)&31.
// ---------------------------------------------------------------------------
static __device__ inline void sa_group(const i32x4 v, const u32x4 tb,
                                       const float T, const int lane,
                                       float& s1, float& s2,
                                       unsigned* __restrict__ bgrp) {
    unsigned long long m0 = __ballot(v.x != 0);
    unsigned long long m1 = __ballot(v.y != 0);
    unsigned long long m2 = __ballot(v.z != 0);
    unsigned long long m3 = __ballot(v.w != 0);
    if (lane == 0) {
        u32x4 w;
        w.x = (unsigned)m0; w.y = (unsigned)m1;
        w.z = (unsigned)m2; w.w = (unsigned)m3;
        *(u32x4*)(bgrp) = w;
    } else if (lane == 32) {
        u32x4 w;
        w.x = (unsigned)(m0 >> 32); w.y = (unsigned)(m1 >> 32);
        w.z = (unsigned)(m2 >> 32); w.w = (unsigned)(m3 >> 32);
        *(u32x4*)(bgrp + 4) = w;
    }
    float e1, e2; bool px;
    e1 = __uint_as_float(tb.x << 16); e2 = __uint_as_float(tb.x & 0xffff0000u);
    px = (e1 >= T);
    s1 += (v.x && px) ? e1 : 0.f;  s2 += (v.x && !px) ? e2 : 0.f;
    e1 = __uint_as_float(tb.y << 16); e2 = __uint_as_float(tb.y & 0xffff0000u);
    px = (e1 >= T);
    s1 += (v.y && px) ? e1 : 0.f;  s2 += (v.y && !px) ? e2 : 0.f;
    e1 = __uint_as_float(tb.z << 16); e2 = __uint_as_float(tb.z & 0xffff0000u);
    px = (e1 >= T);
    s1 += (v.z && px) ? e1 : 0.f;  s2 += (v.z && !px) ? e2 : 0.f;
    e1 = __uint_as_float(tb.w << 16); e2 = __uint_as_float(tb.w & 0xffff0000u);
    px = (e1 >= T);
    s1 += (v.w && px) ? e1 : 0.f;  s2 += (v.w && !px) ? e2 : 0.f;
}

__global__ __launch_bounds__(256) void sa_scan(const int* __restrict__ adj,
                                               const float* __restrict__ a1g,
                                               const unsigned* __restrict__ pku,
                                               unsigned* __restrict__ bm,
                                               float* __restrict__ crow) {
    const int wid = threadIdx.x >> 6, lane = threadIdx.x & 63;
    const int i = blockIdx.x * 4 + wid;
    const float a1i = a1g[i];
    const float T = expf(-a1i);
    const int* arow = adj + (size_t)i * NN;
    unsigned* brow = bm + (size_t)i * (NN / 32);

    float s1 = 0.f, s2 = 0.f;
    for (int it = 0; it < NN / 1024; ++it) {
        const int j0 = it * 1024 + lane * 4;
        i32x4 v0 = __builtin_nontemporal_load((const i32x4*)(arow + j0));
        i32x4 v1 = __builtin_nontemporal_load((const i32x4*)(arow + j0 + 256));
        i32x4 v2 = __builtin_nontemporal_load((const i32x4*)(arow + j0 + 512));
        i32x4 v3 = __builtin_nontemporal_load((const i32x4*)(arow + j0 + 768));
        u32x4 t0 = *(const u32x4*)(pku + j0);
        u32x4 t1 = *(const u32x4*)(pku + j0 + 256);
        u32x4 t2 = *(const u32x4*)(pku + j0 + 512);
        u32x4 t3 = *(const u32x4*)(pku + j0 + 768);
        unsigned* bsup = brow + it * 32;
        sa_group(v0, t0, T, lane, s1, s2, bsup);
        sa_group(v1, t1, T, lane, s1, s2, bsup + 8);
        sa_group(v2, t2, T, lane, s1, s2, bsup + 16);
        sa_group(v3, t3, T, lane, s1, s2, bsup + 24);
    }
    #pragma unroll
    for (int o = 32; o >= 1; o >>= 1) {
        s1 += __shfl_xor(s1, o, 64);
        s2 += __shfl_xor(s2, o, 64);
    }
    if (lane == 0) {
        float c1 = 0.f, c2 = 0.f;
        if (s1 + s2 > 0.f) {
            float e1v = expf(a1i);
            float e2v = expf(0.2f * a1i);
            float S = e1v * s1 + e2v * s2;
            c1 = e1v / S;
            c2 = e2v / S;
        }
        crow[i * 4 + 0] = c1;
        crow[i * 4 + 1] = c2;
        crow[i * 4 + 2] = T;
        crow[i * 4 + 3] = 0.f;
    }
}

// ---------------------------------------------------------------------------
// SB: fused alpha-write + PV MFMA, split-K. grid (NN/64, 8), 512 threads,
// <=64 VGPR, LDS = abuf only -> 4 blocks/CU. Wave owns 32 rows x 32 dims.
// vs r15: part stored as BF16 (halves split-K partial traffic 32->16 MB).
// ---------------------------------------------------------------------------
__global__ __launch_bounds__(512, 8) void sb_pv(const unsigned* __restrict__ bm,
                                                const float* __restrict__ crowG,
                                                const unsigned* __restrict__ pku,
                                                const __hip_bfloat16* __restrict__ whbT,
                                                float* __restrict__ alpha,
                                                unsigned short* __restrict__ part) {
    __shared__ __hip_bfloat16 abuf[2][RPB][KC + 8];      // 34.8 KB (sole LDS)

    const int tid = threadIdx.x;
    const int wv = tid >> 6, lane = tid & 63;
    const int r0 = blockIdx.x * RPB;
    const int ks = blockIdx.y;
    const int k0 = ks * KSL;

    const int rloc = tid >> 5;
    float c1r[4], c2r[4], Tr[4];
    #pragma unroll
    for (int v = 0; v < 4; ++v) {
        f32x4 cw = *(const f32x4*)(crowG + (size_t)(r0 + rloc + 16 * v) * 4);
        c1r[v] = cw.x; c2r[v] = cw.y; Tr[v] = cw.z;
    }

    const int rt2 = wv & 1;              // row half
    const int n0 = (wv >> 1) * 32;       // dim quarter
    f32x4 acc[2][2];
    #pragma unroll
    for (int rp = 0; rp < 2; ++rp)
        #pragma unroll
        for (int nn = 0; nn < 2; ++nn)
            acc[rp][nn] = (f32x4){0.f, 0.f, 0.f, 0.f};

    const short* wb = reinterpret_cast<const short*>(whbT);
    const short* bbase = wb + (size_t)(n0 + (lane & 15)) * 8 + (size_t)(lane >> 4) * 1024;

    const int cgrp = (tid & 31) << 2;
    const unsigned pbit = tid & 31;

    for (int kc = 0; kc < KSL; kc += KC) {
        const int dbuf = (kc >> 7) & 1;
        const int jl = kc + cgrp;
        const int j = k0 + jl;
        const int wbw = ((jl >> 8) << 3) + (((jl >> 7) & 1) << 2);
        u32x4 tb = *(const u32x4*)(pku + j);
        float e1c[4], e2c[4];
        e1c[0] = __uint_as_float(tb.x << 16); e2c[0] = __uint_as_float(tb.x & 0xffff0000u);
        e1c[1] = __uint_as_float(tb.y << 16); e2c[1] = __uint_as_float(tb.y & 0xffff0000u);
        e1c[2] = __uint_as_float(tb.z << 16); e2c[2] = __uint_as_float(tb.z & 0xffff0000u);
        e1c[3] = __uint_as_float(tb.w << 16); e2c[3] = __uint_as_float(tb.w & 0xffff0000u);
        #pragma unroll
        for (int v = 0; v < 4; ++v) {
            const int r = rloc + 16 * v;
            const int gr = r0 + r;
            u32x4 w4 = *(const u32x4*)(bm + (size_t)gr * (NN / 32) + ks * (KSL / 32) + wbw);
            const float c1 = c1r[v], c2 = c2r[v], T = Tr[v];
            f32x4 al;
            al.x = ((w4.x >> pbit) & 1) ? ((e1c[0] >= T) ? c1 * e1c[0] : c2 * e2c[0]) : 0.f;
            al.y = ((w4.y >> pbit) & 1) ? ((e1c[1] >= T) ? c1 * e1c[1] : c2 * e2c[1]) : 0.f;
            al.z = ((w4.z >> pbit) & 1) ? ((e1c[2] >= T) ? c1 * e1c[2] : c2 * e2c[2]) : 0.f;
            al.w = ((w4.w >> pbit) & 1) ? ((e1c[3] >= T) ? c1 * e1c[3] : c2 * e2c[3]) : 0.f;
            __builtin_nontemporal_store(al, (f32x4*)(alpha + (size_t)gr * NN + j));
            u16x4 ub4;
            ub4.x = f2bf(al.x); ub4.y = f2bf(al.y); ub4.z = f2bf(al.z); ub4.w = f2bf(al.w);
            *(u16x4*)(&abuf[dbuf][r][cgrp]) = ub4;
        }
        __syncthreads();
        #pragma unroll
        for (int kk = 0; kk < KC; kk += 32) {
            const short* bp = bbase + (size_t)((k0 + kc + kk) >> 3) * 1024;
            bf16x8 b0 = *(const bf16x8*)(bp);
            bf16x8 b1 = *(const bf16x8*)(bp + 128);      // +16 dims
            #pragma unroll
            for (int rp = 0; rp < 2; ++rp) {
                bf16x8 af = *(const bf16x8*)(&abuf[dbuf][rt2 * 32 + rp * 16 + (lane & 15)]
                                                   [kk + 8 * (lane >> 4)]);
                acc[rp][0] = __builtin_amdgcn_mfma_f32_16x16x32_bf16(af, b0, acc[rp][0], 0, 0, 0);
                acc[rp][1] = __builtin_amdgcn_mfma_f32_16x16x32_bf16(af, b1, acc[rp][1], 0, 0, 0);
            }
        }
    }

    unsigned short* pb2 = part + (size_t)ks * NN * DIM;
    const int rb = (lane >> 4) * 4;
    #pragma unroll
    for (int rp = 0; rp < 2; ++rp) {
        #pragma unroll
        for (int nn = 0; nn < 2; ++nn) {
            #pragma unroll
            for (int q = 0; q < 4; ++q)
                pb2[(size_t)(r0 + rt2 * 32 + rp * 16 + rb + q) * DIM
                    + n0 + nn * 16 + (lane & 15)] = f2bf(acc[rp][nn][q]);
        }
    }
}

// ---------------------------------------------------------------------------
// K5: reduce bf16 split-K partials -> f32 out (L2-warm reads)
// ---------------------------------------------------------------------------
__global__ __launch_bounds__(256) void k5_reduce(const unsigned short* __restrict__ part,
                                                 float* __restrict__ out) {
    const size_t idx = ((size_t)blockIdx.x * 256 + threadIdx.x) * 4;
    f32x4 s = (f32x4){0.f, 0.f, 0.f, 0.f};
    #pragma unroll
    for (int ks = 0; ks < KS; ++ks) {
        u16x4 p = *(const u16x4*)(part + (size_t)ks * NN * DIM + idx);
        s.x += __uint_as_float((unsigned)p.x << 16);
        s.y += __uint_as_float((unsigned)p.y << 16);
        s.z += __uint_as_float((unsigned)p.z << 16);
        s.w += __uint_as_float((unsigned)p.w << 16);
    }
    *(f32x4*)(out + idx) = s;
}

// ---------------------------------------------------------------------------
extern "C" void kernel_launch(void* const* d_in, const int* in_sizes, int n_in,
                              void* d_out, int out_size, void* d_ws, size_t ws_size,
                              hipStream_t stream) {
    const float* h   = (const float*)d_in[0];
    const int*   adj = (const int*)d_in[1];
    const float* W   = (const float*)d_in[2];
    const float* a   = (const float*)d_in[3];

    float* out   = (float*)d_out;
    float* alpha = out + (size_t)NN * DIM;

    char* ws = (char*)d_ws;
    __hip_bfloat16* whbT = (__hip_bfloat16*)(ws);          // 2 MB
    float* a1g    = (float*)(ws + 0x200000);               // 32 KB
    unsigned* pku = (unsigned*)(ws + 0x208000);            // 32 KB
    float* crow   = (float*)(ws + 0x218000);               // 128 KB
    unsigned* bm  = (unsigned*)(ws + 0x240000);            // 8 MB
    unsigned short* part = (unsigned short*)(ws + 0xA40000); // KS*2 MB = 16 MB

    k1m<<<NN / 64, 256, 0, stream>>>(h, W, a, whbT, a1g, pku);
    sa_scan<<<NN / 4, 256, 0, stream>>>(adj, a1g, pku, bm, crow);
    sb_pv<<<dim3(NN / RPB, KS), 512, 0, stream>>>(bm, crow, pku, whbT, alpha, part);
    k5_reduce<<<NN * DIM / 1024, 256, 0, stream>>>(part, out);
}